// Round 1
// baseline (154.407 us; speedup 1.0000x reference)
//
#include <hip/hip_runtime.h>
#include <hip/hip_bf16.h>

typedef __bf16 bf16;
typedef __bf16 bf16x4 __attribute__((ext_vector_type(4)));
typedef __bf16 bf16x8 __attribute__((ext_vector_type(8)));
typedef float f32x4 __attribute__((ext_vector_type(4)));

#define NB 8
#define NT 2048
#define NC 1024
#define NH 64

__device__ inline f32x4 zero4() {
    f32x4 z; z[0] = 0.f; z[1] = 0.f; z[2] = 0.f; z[3] = 0.f; return z;
}

// ---------------- pack W: Wq|Wk|Wv (f32 [C][H]) -> Wt bf16 [192][C] (B^T layout) ----
// rows 0-63 = Wq^T, 64-127 = Wk^T, 128-191 = Wv^T
__global__ __launch_bounds__(256) void pack_w(const float* __restrict__ Wq,
                                              const float* __restrict__ Wk,
                                              const float* __restrict__ Wv,
                                              bf16* __restrict__ Wt) {
    const int idx = blockIdx.x * 256 + threadIdx.x;   // n*1024 + c
    const int n = idx >> 10;
    const int c = idx & 1023;
    const float* W = (n < 64) ? Wq : (n < 128) ? Wk : Wv;
    Wt[idx] = (bf16)W[c * NH + (n & 63)];
}

// ---------------- QKV projection: x[16384][1024] f32 @ Wt -> q,k (bf16 [16384][64]), vT (bf16 [8][64][2048])
__global__ __launch_bounds__(256) void qkv_gemm(const float* __restrict__ x,
                                                const bf16* __restrict__ Wt,
                                                bf16* __restrict__ qp,
                                                bf16* __restrict__ kp,
                                                bf16* __restrict__ vt) {
    __shared__ bf16 xs[64][72];   // +8 pad: breaks 16-way bank conflict on a-frag reads
    const int tid = threadIdx.x;
    const int wave = tid >> 6, lane = tid & 63;
    const int l16 = lane & 15, lhi = lane >> 4;
    const int row0 = blockIdx.x * 64;

    f32x4 acc[12];
#pragma unroll
    for (int nf = 0; nf < 12; ++nf) acc[nf] = zero4();

    const int sr = tid >> 4;           // staging row (+ i*16)
    const int sc = (tid & 15) * 4;     // staging col (f32)

    for (int kt = 0; kt < 16; ++kt) {
        const int k0 = kt * 64;
        // load 4 float4 per thread, convert to bf16
        float4 v[4];
#pragma unroll
        for (int i = 0; i < 4; ++i)
            v[i] = *reinterpret_cast<const float4*>(
                &x[(size_t)(row0 + sr + i * 16) * NC + k0 + sc]);
        __syncthreads();   // prior iteration's LDS reads complete before overwrite
#pragma unroll
        for (int i = 0; i < 4; ++i) {
            bf16x4 bv;
            bv[0] = (bf16)v[i].x; bv[1] = (bf16)v[i].y;
            bv[2] = (bf16)v[i].z; bv[3] = (bf16)v[i].w;
            *reinterpret_cast<bf16x4*>(&xs[sr + i * 16][sc]) = bv;
        }
        __syncthreads();

        bf16x8 a[2];
#pragma unroll
        for (int kc = 0; kc < 2; ++kc)
            a[kc] = *reinterpret_cast<const bf16x8*>(
                &xs[wave * 16 + l16][kc * 32 + lhi * 8]);
#pragma unroll
        for (int nf = 0; nf < 12; ++nf) {
#pragma unroll
            for (int kc = 0; kc < 2; ++kc) {
                const bf16x8 b = *reinterpret_cast<const bf16x8*>(
                    &Wt[(size_t)(nf * 16 + l16) * NC + k0 + kc * 32 + lhi * 8]);
                acc[nf] = __builtin_amdgcn_mfma_f32_16x16x32_bf16(a[kc], b, acc[nf], 0, 0, 0);
            }
        }
    }

    // epilogue: cols 0-63 -> q, 64-127 -> k, 128-191 -> v (transposed store)
#pragma unroll
    for (int nf = 0; nf < 12; ++nf) {
        const int col = nf * 16 + l16;
#pragma unroll
        for (int r = 0; r < 4; ++r) {
            const int row = row0 + wave * 16 + lhi * 4 + r;
            const bf16 val = (bf16)acc[nf][r];
            if (col < 64) {
                qp[(size_t)row * NH + col] = val;
            } else if (col < 128) {
                kp[(size_t)row * NH + (col - 64)] = val;
            } else {
                const int bb = row >> 11, t = row & (NT - 1), h = col - 128;
                vt[(((size_t)bb * NH + h) << 11) + t] = val;
            }
        }
    }
}

// ---------------- fused flash attention ----------------
// grid (32, 8): blockIdx.x = q-tile of 64 rows, blockIdx.y = batch. 4 waves x 16 q-rows.
__global__ __launch_bounds__(256) void attn(const bf16* __restrict__ qp,
                                            const bf16* __restrict__ kp,
                                            const bf16* __restrict__ vt,
                                            const int* __restrict__ mask,
                                            float* __restrict__ out) {
    __shared__ bf16 p_lds[4][16][80];   // per-wave private P re-layout buffer (+16 pad)
    const int tid = threadIdx.x;
    const int wave = tid >> 6, lane = tid & 63;
    const int l16 = lane & 15, lhi = lane >> 4;
    const int b = blockIdx.y;
    const int q0 = blockIdx.x * 64 + wave * 16;   // this wave's 16 q-rows

    // Q fragments (held for whole kernel)
    bf16x8 aq[2];
#pragma unroll
    for (int hc = 0; hc < 2; ++hc)
        aq[hc] = *reinterpret_cast<const bf16x8*>(
            &qp[((size_t)b * NT + q0 + l16) * NH + hc * 32 + lhi * 8]);

    float m_r[4], l_r[4];
    f32x4 o[4];
#pragma unroll
    for (int r = 0; r < 4; ++r) { m_r[r] = -1e30f; l_r[r] = 0.f; }
#pragma unroll
    for (int hb = 0; hb < 4; ++hb) o[hb] = zero4();

    for (int kv0 = 0; kv0 < NT; kv0 += 64) {
        // S = Q K^T for 16 q-rows x 64 kv-cols
        f32x4 s[4];
#pragma unroll
        for (int kvb = 0; kvb < 4; ++kvb) {
            s[kvb] = zero4();
#pragma unroll
            for (int hc = 0; hc < 2; ++hc) {
                const bf16x8 bk = *reinterpret_cast<const bf16x8*>(
                    &kp[((size_t)b * NT + kv0 + kvb * 16 + l16) * NH + hc * 32 + lhi * 8]);
                s[kvb] = __builtin_amdgcn_mfma_f32_16x16x32_bf16(aq[hc], bk, s[kvb], 0, 0, 0);
            }
        }
        // scale + mask (mask indexed by key position)
#pragma unroll
        for (int kvb = 0; kvb < 4; ++kvb) {
            const int mk = mask[b * NT + kv0 + kvb * 16 + l16];
#pragma unroll
            for (int r = 0; r < 4; ++r)
                s[kvb][r] = mk ? s[kvb][r] * 0.125f : -1e30f;
        }
        // row max over tile: 4 local frags then 16-lane-group butterfly
        float tm[4];
#pragma unroll
        for (int r = 0; r < 4; ++r)
            tm[r] = fmaxf(fmaxf(s[0][r], s[1][r]), fmaxf(s[2][r], s[3][r]));
#pragma unroll
        for (int r = 0; r < 4; ++r) {
            tm[r] = fmaxf(tm[r], __shfl_xor(tm[r], 1));
            tm[r] = fmaxf(tm[r], __shfl_xor(tm[r], 2));
            tm[r] = fmaxf(tm[r], __shfl_xor(tm[r], 4));
            tm[r] = fmaxf(tm[r], __shfl_xor(tm[r], 8));
        }
        float alpha[4], ps[4];
#pragma unroll
        for (int r = 0; r < 4; ++r) {
            const float mn = fmaxf(m_r[r], tm[r]);
            alpha[r] = __expf(m_r[r] - mn);
            m_r[r] = mn;
            ps[r] = 0.f;
        }
        // P = exp(S - m), row sums
#pragma unroll
        for (int kvb = 0; kvb < 4; ++kvb)
#pragma unroll
            for (int r = 0; r < 4; ++r) {
                const float p = __expf(s[kvb][r] - m_r[r]);
                s[kvb][r] = p;
                ps[r] += p;
            }
#pragma unroll
        for (int r = 0; r < 4; ++r) {
            ps[r] += __shfl_xor(ps[r], 1);
            ps[r] += __shfl_xor(ps[r], 2);
            ps[r] += __shfl_xor(ps[r], 4);
            ps[r] += __shfl_xor(ps[r], 8);
            l_r[r] = l_r[r] * alpha[r] + ps[r];
        }
        // P (D-layout) -> LDS -> A-layout
        __syncthreads();   // WAR: prior tile's PV reads done before overwrite
#pragma unroll
        for (int kvb = 0; kvb < 4; ++kvb)
#pragma unroll
            for (int r = 0; r < 4; ++r)
                p_lds[wave][lhi * 4 + r][kvb * 16 + l16] = (bf16)s[kvb][r];
        __syncthreads();
        // rescale O, then O += P V
#pragma unroll
        for (int hb = 0; hb < 4; ++hb)
#pragma unroll
            for (int r = 0; r < 4; ++r)
                o[hb][r] *= alpha[r];
#pragma unroll
        for (int kc = 0; kc < 2; ++kc) {
            const bf16x8 ap = *reinterpret_cast<const bf16x8*>(
                &p_lds[wave][l16][kc * 32 + lhi * 8]);
#pragma unroll
            for (int hb = 0; hb < 4; ++hb) {
                const bf16x8 bv = *reinterpret_cast<const bf16x8*>(
                    &vt[((size_t)b * NH + hb * 16 + l16) * NT + kv0 + kc * 32 + lhi * 8]);
                o[hb] = __builtin_amdgcn_mfma_f32_16x16x32_bf16(ap, bv, o[hb], 0, 0, 0);
            }
        }
    }
    // epilogue: out = O / l  (f32)
#pragma unroll
    for (int hb = 0; hb < 4; ++hb)
#pragma unroll
        for (int r = 0; r < 4; ++r) {
            const int row = q0 + lhi * 4 + r;
            out[((size_t)b * NT + row) * NH + hb * 16 + l16] = o[hb][r] / l_r[r];
        }
}

extern "C" void kernel_launch(void* const* d_in, const int* in_sizes, int n_in,
                              void* d_out, int out_size, void* d_ws, size_t ws_size,
                              hipStream_t stream) {
    const float* x    = (const float*)d_in[0];
    const int*   mask = (const int*)d_in[1];
    const float* Wk   = (const float*)d_in[2];
    const float* Wq   = (const float*)d_in[3];
    const float* Wv   = (const float*)d_in[4];
    float* out = (float*)d_out;

    char* ws = (char*)d_ws;
    bf16* Wt = (bf16*)(ws);                                   // 384 KiB
    bf16* qp = (bf16*)(ws + (512 << 10));                     // 2 MiB
    bf16* kp = (bf16*)(ws + (512 << 10) + (2 << 20));         // 2 MiB
    bf16* vt = (bf16*)(ws + (512 << 10) + (4 << 20));         // 2 MiB

    pack_w<<<dim3(768), dim3(256), 0, stream>>>(Wq, Wk, Wv, Wt);
    qkv_gemm<<<dim3(256), dim3(256), 0, stream>>>(x, Wt, qp, kp, vt);
    attn<<<dim3(32, 8), dim3(256), 0, stream>>>(qp, kp, vt, mask, out);
}

// Round 2
// 141.675 us; speedup vs baseline: 1.0899x; 1.0899x over previous
//
#include <hip/hip_runtime.h>
#include <hip/hip_bf16.h>

typedef __bf16 bf16;
typedef __bf16 bf16x4 __attribute__((ext_vector_type(4)));
typedef __bf16 bf16x8 __attribute__((ext_vector_type(8)));
typedef float f32x4 __attribute__((ext_vector_type(4)));

#define NB 8
#define NT 2048
#define NC 1024
#define NH 64

__device__ inline f32x4 zero4() {
    f32x4 z; z[0] = 0.f; z[1] = 0.f; z[2] = 0.f; z[3] = 0.f; return z;
}

// ---------------- pack W: Wq|Wk|Wv (f32 [C][H]) -> Wt bf16 [192][C] (B^T layout) ----
__global__ __launch_bounds__(256) void pack_w(const float* __restrict__ Wq,
                                              const float* __restrict__ Wk,
                                              const float* __restrict__ Wv,
                                              bf16* __restrict__ Wt) {
    const int idx = blockIdx.x * 256 + threadIdx.x;   // n*1024 + c
    const int n = idx >> 10;
    const int c = idx & 1023;
    const float* W = (n < 64) ? Wq : (n < 128) ? Wk : Wv;
    Wt[idx] = (bf16)W[c * NH + (n & 63)];
}

// ---------------- QKV projection ----------------
// 512 threads = 8 waves: wave = qgroup(4) x colhalf(2). Block computes 64 rows x 192 cols.
__global__ __launch_bounds__(512) void qkv_gemm(const float* __restrict__ x,
                                                const bf16* __restrict__ Wt,
                                                bf16* __restrict__ qp,
                                                bf16* __restrict__ kp,
                                                bf16* __restrict__ vt) {
    __shared__ bf16 xs[64][72];   // +8 pad
    const int tid = threadIdx.x;
    const int wave = tid >> 6, lane = tid & 63;
    const int l16 = lane & 15, lhi = lane >> 4;
    const int qg = wave & 3;      // 16-row group
    const int ch = wave >> 2;     // 96-col half
    const int row0 = blockIdx.x * 64;

    f32x4 acc[6];
#pragma unroll
    for (int nf = 0; nf < 6; ++nf) acc[nf] = zero4();

    const int sr = tid >> 4;           // 0..31 (+32 for second chunk)
    const int sc = (tid & 15) * 4;     // f32 col

    for (int kt = 0; kt < 16; ++kt) {
        const int k0 = kt * 64;
        float4 v[2];
#pragma unroll
        for (int i = 0; i < 2; ++i)
            v[i] = *reinterpret_cast<const float4*>(
                &x[(size_t)(row0 + sr + i * 32) * NC + k0 + sc]);
        __syncthreads();   // prior iteration's LDS reads complete
#pragma unroll
        for (int i = 0; i < 2; ++i) {
            bf16x4 bv;
            bv[0] = (bf16)v[i].x; bv[1] = (bf16)v[i].y;
            bv[2] = (bf16)v[i].z; bv[3] = (bf16)v[i].w;
            *reinterpret_cast<bf16x4*>(&xs[sr + i * 32][sc]) = bv;
        }
        __syncthreads();

        bf16x8 a[2];
#pragma unroll
        for (int kc = 0; kc < 2; ++kc)
            a[kc] = *reinterpret_cast<const bf16x8*>(
                &xs[qg * 16 + l16][kc * 32 + lhi * 8]);
#pragma unroll
        for (int nf = 0; nf < 6; ++nf) {
#pragma unroll
            for (int kc = 0; kc < 2; ++kc) {
                const bf16x8 b = *reinterpret_cast<const bf16x8*>(
                    &Wt[(size_t)(ch * 96 + nf * 16 + l16) * NC + k0 + kc * 32 + lhi * 8]);
                acc[nf] = __builtin_amdgcn_mfma_f32_16x16x32_bf16(a[kc], b, acc[nf], 0, 0, 0);
            }
        }
    }

#pragma unroll
    for (int nf = 0; nf < 6; ++nf) {
        const int col = ch * 96 + nf * 16 + l16;
#pragma unroll
        for (int r = 0; r < 4; ++r) {
            const int row = row0 + qg * 16 + lhi * 4 + r;
            const bf16 val = (bf16)acc[nf][r];
            if (col < 64) {
                qp[(size_t)row * NH + col] = val;
            } else if (col < 128) {
                kp[(size_t)row * NH + (col - 64)] = val;
            } else {
                const int bb = row >> 11, t = row & (NT - 1), h = col - 128;
                vt[(((size_t)bb * NH + h) << 11) + t] = val;
            }
        }
    }
}

// ---------------- fused flash attention, in-block KV split ----------------
// grid (64, 8): 32 q-rows per block. 512 threads = 8 waves = qgroup(2) x kvsplit(4).
// Each wave: 16 q-rows over 512 KV. LDS-combine at the end.
__global__ __launch_bounds__(512) void attn(const bf16* __restrict__ qp,
                                            const bf16* __restrict__ kp,
                                            const bf16* __restrict__ vt,
                                            const int* __restrict__ mask,
                                            float* __restrict__ out) {
    __shared__ __align__(16) char smem[4 * 2 * 16 * 68 * 4];   // 34816 B
    bf16 (*p_lds)[16][80] = reinterpret_cast<bf16 (*)[16][80]>(smem);    // [8][16][80] = 20480 B
    float (*sm_o)[2][16][68] = reinterpret_cast<float (*)[2][16][68]>(smem);
    __shared__ float sm_m[4][2][16], sm_l[4][2][16];

    const int tid = threadIdx.x;
    const int wave = tid >> 6, lane = tid & 63;
    const int l16 = lane & 15, lhi = lane >> 4;
    const int b = blockIdx.y;
    const int qg = wave & 1, sp = wave >> 1;
    const int q0 = blockIdx.x * 32 + qg * 16;
    const int kv_lo = sp * 512;

    bf16x8 aq[2];
#pragma unroll
    for (int hc = 0; hc < 2; ++hc)
        aq[hc] = *reinterpret_cast<const bf16x8*>(
            &qp[((size_t)b * NT + q0 + l16) * NH + hc * 32 + lhi * 8]);

    float m_r[4], l_r[4];
    f32x4 o[4];
#pragma unroll
    for (int r = 0; r < 4; ++r) { m_r[r] = -1e30f; l_r[r] = 0.f; }
#pragma unroll
    for (int hb = 0; hb < 4; ++hb) o[hb] = zero4();

    for (int it = 0; it < 8; ++it) {
        const int kv0 = kv_lo + it * 64;
        f32x4 s[4];
#pragma unroll
        for (int kvb = 0; kvb < 4; ++kvb) {
            s[kvb] = zero4();
#pragma unroll
            for (int hc = 0; hc < 2; ++hc) {
                const bf16x8 bk = *reinterpret_cast<const bf16x8*>(
                    &kp[((size_t)b * NT + kv0 + kvb * 16 + l16) * NH + hc * 32 + lhi * 8]);
                s[kvb] = __builtin_amdgcn_mfma_f32_16x16x32_bf16(aq[hc], bk, s[kvb], 0, 0, 0);
            }
        }
#pragma unroll
        for (int kvb = 0; kvb < 4; ++kvb) {
            const int mk = mask[b * NT + kv0 + kvb * 16 + l16];
#pragma unroll
            for (int r = 0; r < 4; ++r)
                s[kvb][r] = mk ? s[kvb][r] * 0.125f : -1e30f;
        }
        float tm[4];
#pragma unroll
        for (int r = 0; r < 4; ++r)
            tm[r] = fmaxf(fmaxf(s[0][r], s[1][r]), fmaxf(s[2][r], s[3][r]));
#pragma unroll
        for (int r = 0; r < 4; ++r) {
            tm[r] = fmaxf(tm[r], __shfl_xor(tm[r], 1));
            tm[r] = fmaxf(tm[r], __shfl_xor(tm[r], 2));
            tm[r] = fmaxf(tm[r], __shfl_xor(tm[r], 4));
            tm[r] = fmaxf(tm[r], __shfl_xor(tm[r], 8));
        }
        float alpha[4], ps[4];
#pragma unroll
        for (int r = 0; r < 4; ++r) {
            const float mn = fmaxf(m_r[r], tm[r]);
            alpha[r] = __expf(m_r[r] - mn);
            m_r[r] = mn;
            ps[r] = 0.f;
        }
#pragma unroll
        for (int kvb = 0; kvb < 4; ++kvb)
#pragma unroll
            for (int r = 0; r < 4; ++r) {
                const float p = __expf(s[kvb][r] - m_r[r]);
                s[kvb][r] = p;
                ps[r] += p;
            }
#pragma unroll
        for (int r = 0; r < 4; ++r) {
            ps[r] += __shfl_xor(ps[r], 1);
            ps[r] += __shfl_xor(ps[r], 2);
            ps[r] += __shfl_xor(ps[r], 4);
            ps[r] += __shfl_xor(ps[r], 8);
            l_r[r] = l_r[r] * alpha[r] + ps[r];
        }
        __syncthreads();   // WAR on p_lds
#pragma unroll
        for (int kvb = 0; kvb < 4; ++kvb)
#pragma unroll
            for (int r = 0; r < 4; ++r)
                p_lds[wave][lhi * 4 + r][kvb * 16 + l16] = (bf16)s[kvb][r];
        __syncthreads();
#pragma unroll
        for (int hb = 0; hb < 4; ++hb)
#pragma unroll
            for (int r = 0; r < 4; ++r)
                o[hb][r] *= alpha[r];
#pragma unroll
        for (int kc = 0; kc < 2; ++kc) {
            const bf16x8 ap = *reinterpret_cast<const bf16x8*>(
                &p_lds[wave][l16][kc * 32 + lhi * 8]);
#pragma unroll
            for (int hb = 0; hb < 4; ++hb) {
                const bf16x8 bv = *reinterpret_cast<const bf16x8*>(
                    &vt[((size_t)b * NH + hb * 16 + l16) * NT + kv0 + kc * 32 + lhi * 8]);
                o[hb] = __builtin_amdgcn_mfma_f32_16x16x32_bf16(ap, bv, o[hb], 0, 0, 0);
            }
        }
    }

    // ---- combine the 4 KV splits through LDS ----
    __syncthreads();   // all waves done with p_lds region (aliased by sm_o)
#pragma unroll
    for (int hb = 0; hb < 4; ++hb)
#pragma unroll
        for (int r = 0; r < 4; ++r)
            sm_o[sp][qg][lhi * 4 + r][hb * 16 + l16] = o[hb][r];
    if (l16 == 0) {
#pragma unroll
        for (int r = 0; r < 4; ++r) {
            sm_m[sp][qg][lhi * 4 + r] = m_r[r];
            sm_l[sp][qg][lhi * 4 + r] = l_r[r];
        }
    }
    __syncthreads();

#pragma unroll
    for (int e = 0; e < 4; ++e) {
        const int idx = e * 512 + tid;      // 0..2047
        const int row = idx >> 6;           // 0..31
        const int col = idx & 63;
        const int qg2 = row >> 4, r16 = row & 15;
        float M = sm_m[0][qg2][r16];
#pragma unroll
        for (int s2 = 1; s2 < 4; ++s2) M = fmaxf(M, sm_m[s2][qg2][r16]);
        float L = 0.f, accv = 0.f;
#pragma unroll
        for (int s2 = 0; s2 < 4; ++s2) {
            const float w = __expf(sm_m[s2][qg2][r16] - M);
            L += w * sm_l[s2][qg2][r16];
            accv += w * sm_o[s2][qg2][r16][col];
        }
        out[((size_t)b * NT + blockIdx.x * 32 + row) * NH + col] = accv / L;
    }
}

extern "C" void kernel_launch(void* const* d_in, const int* in_sizes, int n_in,
                              void* d_out, int out_size, void* d_ws, size_t ws_size,
                              hipStream_t stream) {
    const float* x    = (const float*)d_in[0];
    const int*   mask = (const int*)d_in[1];
    const float* Wk   = (const float*)d_in[2];
    const float* Wq   = (const float*)d_in[3];
    const float* Wv   = (const float*)d_in[4];
    float* out = (float*)d_out;

    char* ws = (char*)d_ws;
    bf16* Wt = (bf16*)(ws);                                   // 384 KiB
    bf16* qp = (bf16*)(ws + (512 << 10));                     // 2 MiB
    bf16* kp = (bf16*)(ws + (512 << 10) + (2 << 20));         // 2 MiB
    bf16* vt = (bf16*)(ws + (512 << 10) + (4 << 20));         // 2 MiB

    pack_w<<<dim3(768), dim3(256), 0, stream>>>(Wq, Wk, Wv, Wt);
    qkv_gemm<<<dim3(256), dim3(512), 0, stream>>>(x, Wt, qp, kp, vt);
    attn<<<dim3(64, 8), dim3(512), 0, stream>>>(qp, kp, vt, mask, out);
}

// Round 3
// 127.466 us; speedup vs baseline: 1.2114x; 1.1115x over previous
//
#include <hip/hip_runtime.h>
#include <hip/hip_bf16.h>

typedef __bf16 bf16;
typedef __bf16 bf16x4 __attribute__((ext_vector_type(4)));
typedef __bf16 bf16x8 __attribute__((ext_vector_type(8)));
typedef float f32x4 __attribute__((ext_vector_type(4)));

#define NB 8
#define NT 2048
#define NC 1024
#define NH 64

__device__ inline f32x4 zero4() {
    f32x4 z; z[0] = 0.f; z[1] = 0.f; z[2] = 0.f; z[3] = 0.f; return z;
}

// ---------------- pack W: Wq|Wk|Wv (f32 [C][H]) -> Wt bf16 [192][C] (B^T layout) ----
__global__ __launch_bounds__(256) void pack_w(const float* __restrict__ Wq,
                                              const float* __restrict__ Wk,
                                              const float* __restrict__ Wv,
                                              bf16* __restrict__ Wt) {
    const int idx = blockIdx.x * 256 + threadIdx.x;   // n*1024 + c
    const int n = idx >> 10;
    const int c = idx & 1023;
    const float* W = (n < 64) ? Wq : (n < 128) ? Wk : Wv;
    Wt[idx] = (bf16)W[c * NH + (n & 63)];
}

// ---------------- QKV projection ----------------
// 512 blocks x 256 threads. Block = 32 rows x 192 cols. Wave: qg(2) x ch(2, 96 cols).
// Double-buffered LDS, 1 barrier/iter, x-prefetch issued AFTER the barrier so its
// latency hides under the B-load + MFMA phase (not drained by the barrier vmcnt(0)).
__global__ __launch_bounds__(256) void qkv_gemm(const float* __restrict__ x,
                                                const bf16* __restrict__ Wt,
                                                bf16* __restrict__ qp,
                                                bf16* __restrict__ kp,
                                                bf16* __restrict__ vt) {
    __shared__ bf16 xs[2][32][72];   // 9216 B, +8 pad
    const int tid = threadIdx.x;
    const int wave = tid >> 6, lane = tid & 63;
    const int l16 = lane & 15, lhi = lane >> 4;
    const int qg = wave & 1;      // 16-row group
    const int ch = wave >> 1;     // 96-col half
    const int row0 = blockIdx.x * 32;

    f32x4 acc[6];
#pragma unroll
    for (int nf = 0; nf < 6; ++nf) acc[nf] = zero4();

    const int sr = tid >> 4;           // 0..15 (rows sr, sr+16)
    const int sc = (tid & 15) * 4;     // f32 col

    float4 v0 = *reinterpret_cast<const float4*>(&x[(size_t)(row0 + sr) * NC + sc]);
    float4 v1 = *reinterpret_cast<const float4*>(&x[(size_t)(row0 + sr + 16) * NC + sc]);

    for (int kt = 0; kt < 16; ++kt) {
        const int cur = kt & 1;
        const int k0 = kt * 64;
        {
            bf16x4 w0, w1;
            w0[0] = (bf16)v0.x; w0[1] = (bf16)v0.y; w0[2] = (bf16)v0.z; w0[3] = (bf16)v0.w;
            w1[0] = (bf16)v1.x; w1[1] = (bf16)v1.y; w1[2] = (bf16)v1.z; w1[3] = (bf16)v1.w;
            *reinterpret_cast<bf16x4*>(&xs[cur][sr][sc]) = w0;
            *reinterpret_cast<bf16x4*>(&xs[cur][sr + 16][sc]) = w1;
        }
        __syncthreads();
        // prefetch next k-chunk AFTER the barrier: latency hides under B-loads+MFMA
        if (kt < 15) {
            const int kn = k0 + 64;
            v0 = *reinterpret_cast<const float4*>(&x[(size_t)(row0 + sr) * NC + kn + sc]);
            v1 = *reinterpret_cast<const float4*>(&x[(size_t)(row0 + sr + 16) * NC + kn + sc]);
        }
        // B fragments for this k-chunk (L2-resident Wt)
        bf16x8 b2[6][2];
#pragma unroll
        for (int nf = 0; nf < 6; ++nf)
#pragma unroll
            for (int kc = 0; kc < 2; ++kc)
                b2[nf][kc] = *reinterpret_cast<const bf16x8*>(
                    &Wt[(size_t)(ch * 96 + nf * 16 + l16) * NC + k0 + kc * 32 + lhi * 8]);
        bf16x8 a[2];
#pragma unroll
        for (int kc = 0; kc < 2; ++kc)
            a[kc] = *reinterpret_cast<const bf16x8*>(
                &xs[cur][qg * 16 + l16][kc * 32 + lhi * 8]);
#pragma unroll
        for (int nf = 0; nf < 6; ++nf)
#pragma unroll
            for (int kc = 0; kc < 2; ++kc)
                acc[nf] = __builtin_amdgcn_mfma_f32_16x16x32_bf16(a[kc], b2[nf][kc], acc[nf], 0, 0, 0);
    }

#pragma unroll
    for (int nf = 0; nf < 6; ++nf) {
        const int col = ch * 96 + nf * 16 + l16;
#pragma unroll
        for (int r = 0; r < 4; ++r) {
            const int row = row0 + qg * 16 + lhi * 4 + r;
            const bf16 val = (bf16)acc[nf][r];
            if (col < 64) {
                qp[(size_t)row * NH + col] = val;
            } else if (col < 128) {
                kp[(size_t)row * NH + (col - 64)] = val;
            } else {
                const int bb = row >> 11, t = row & (NT - 1), h = col - 128;
                vt[(((size_t)bb * NH + h) << 11) + t] = val;
            }
        }
    }
}

// ---------------- fused flash attention, swapped-QK^T, barrier-free main loop ----
// grid (64, 8): 32 q-rows/block. 512 threads = 8 waves = qg(2) x kvsplit(4).
// Swapped QK^T: s = mfma(A=K, B=Q) -> lane (l16,lhi) holds P[q=l16][kv=kvb*16+lhi*4+r].
// P staged per-wave in A-frag-ordered LDS [64][20] (row = q + 16*((kv>>3)&3),
// col = (kv>>5)*8 + (kv&7)) -> PV A-frag read is 2x ds_read_b64 per kc.
__global__ __launch_bounds__(512, 4) void attn(const bf16* __restrict__ qp,
                                               const bf16* __restrict__ kp,
                                               const bf16* __restrict__ vt,
                                               const int* __restrict__ mask,
                                               float* __restrict__ out) {
    __shared__ __align__(16) char smem[4 * 2 * 16 * 68 * 4];   // 34816 B (union)
    bf16 (*p_lds)[64][20] = reinterpret_cast<bf16 (*)[64][20]>(smem);   // [8][64][20] = 20480 B
    float (*sm_o)[2][16][68] = reinterpret_cast<float (*)[2][16][68]>(smem);
    __shared__ float sm_m[4][2][16], sm_l[4][2][16];

    const int tid = threadIdx.x;
    const int wave = tid >> 6, lane = tid & 63;
    const int l16 = lane & 15, lhi = lane >> 4;
    const int b = blockIdx.y;
    const int qg = wave & 1, sp = wave >> 1;
    const int q0 = blockIdx.x * 32 + qg * 16;
    const int kv_lo = sp * 512;
    bf16* const pw = &p_lds[wave][0][0];

    // Q fragment (B-operand of swapped QK^T, A-operand layout-compatible for nothing else)
    bf16x8 aq[2];
#pragma unroll
    for (int hc = 0; hc < 2; ++hc)
        aq[hc] = *reinterpret_cast<const bf16x8*>(
            &qp[((size_t)b * NT + q0 + l16) * NH + hc * 32 + lhi * 8]);

    float m = -1e30f, l = 0.f;
    f32x4 o[4];
#pragma unroll
    for (int hb = 0; hb < 4; ++hb) o[hb] = zero4();

    for (int it = 0; it < 8; ++it) {
        const int kv0 = kv_lo + it * 64;
        // hoist V + mask loads: latency hides under QK^T + softmax
        bf16x8 bvr[2][4];
#pragma unroll
        for (int kc = 0; kc < 2; ++kc)
#pragma unroll
            for (int hb = 0; hb < 4; ++hb)
                bvr[kc][hb] = *reinterpret_cast<const bf16x8*>(
                    &vt[((size_t)b * NH + hb * 16 + l16) * NT + kv0 + kc * 32 + lhi * 8]);
        int4 mvv[4];
#pragma unroll
        for (int kvb = 0; kvb < 4; ++kvb)
            mvv[kvb] = *reinterpret_cast<const int4*>(&mask[b * NT + kv0 + kvb * 16 + lhi * 4]);

        // S^T tile: A = K rows, B = Q rows
        f32x4 s[4];
#pragma unroll
        for (int kvb = 0; kvb < 4; ++kvb) {
            s[kvb] = zero4();
#pragma unroll
            for (int hc = 0; hc < 2; ++hc) {
                const bf16x8 bk = *reinterpret_cast<const bf16x8*>(
                    &kp[((size_t)b * NT + kv0 + kvb * 16 + l16) * NH + hc * 32 + lhi * 8]);
                s[kvb] = __builtin_amdgcn_mfma_f32_16x16x32_bf16(bk, aq[hc], s[kvb], 0, 0, 0);
            }
        }
        // mask + scale: element r has kv = kv0 + kvb*16 + lhi*4 + r
#pragma unroll
        for (int kvb = 0; kvb < 4; ++kvb) {
            const int mm[4] = {mvv[kvb].x, mvv[kvb].y, mvv[kvb].z, mvv[kvb].w};
#pragma unroll
            for (int r = 0; r < 4; ++r)
                s[kvb][r] = mm[r] ? s[kvb][r] * 0.125f : -1e30f;
        }
        // online softmax for q = l16 (lane-local row)
        float tm = s[0][0];
#pragma unroll
        for (int kvb = 0; kvb < 4; ++kvb)
#pragma unroll
            for (int r = 0; r < 4; ++r) tm = fmaxf(tm, s[kvb][r]);
        tm = fmaxf(tm, __shfl_xor(tm, 16));
        tm = fmaxf(tm, __shfl_xor(tm, 32));
        const float mn = fmaxf(m, tm);
        const float alpha = __expf(m - mn);
        m = mn;
        float ps = 0.f;
#pragma unroll
        for (int kvb = 0; kvb < 4; ++kvb)
#pragma unroll
            for (int r = 0; r < 4; ++r) {
                const float p = __expf(s[kvb][r] - m);
                s[kvb][r] = p;
                ps += p;
            }
        ps += __shfl_xor(ps, 16);
        ps += __shfl_xor(ps, 32);
        l = l * alpha + ps;
        // pack P -> per-wave LDS (A-frag ordered); wave-local, no barrier
#pragma unroll
        for (int kvb = 0; kvb < 4; ++kvb) {
            bf16x4 w;
            w[0] = (bf16)s[kvb][0]; w[1] = (bf16)s[kvb][1];
            w[2] = (bf16)s[kvb][2]; w[3] = (bf16)s[kvb][3];
            const int row = l16 + 16 * ((kvb * 2 + (lhi >> 1)) & 3);
            *reinterpret_cast<bf16x4*>(pw + row * 20 + (kvb >> 1) * 8 + (lhi & 1) * 4) = w;
        }
        // redistribute alpha to O-rows (q = lhi*4 + r), rescale O (overlaps ds_write)
        float ar[4];
#pragma unroll
        for (int r = 0; r < 4; ++r) ar[r] = __shfl(alpha, lhi * 4 + r);
#pragma unroll
        for (int hb = 0; hb < 4; ++hb)
#pragma unroll
            for (int r = 0; r < 4; ++r) o[hb][r] *= ar[r];
        // O += P V
#pragma unroll
        for (int kc = 0; kc < 2; ++kc) {
            const bf16* pr = pw + lane * 20 + kc * 8;
            const bf16x4 lo = *reinterpret_cast<const bf16x4*>(pr);
            const bf16x4 hi = *reinterpret_cast<const bf16x4*>(pr + 4);
            const bf16x8 pa = __builtin_shufflevector(lo, hi, 0, 1, 2, 3, 4, 5, 6, 7);
#pragma unroll
            for (int hb = 0; hb < 4; ++hb)
                o[hb] = __builtin_amdgcn_mfma_f32_16x16x32_bf16(pa, bvr[kc][hb], o[hb], 0, 0, 0);
        }
    }

    // ---- combine the 4 KV splits through LDS ----
    __syncthreads();   // all waves done with p_lds (aliased by sm_o)
#pragma unroll
    for (int hb = 0; hb < 4; ++hb)
#pragma unroll
        for (int r = 0; r < 4; ++r)
            sm_o[sp][qg][lhi * 4 + r][hb * 16 + l16] = o[hb][r];
    if (lhi == 0) {
        sm_m[sp][qg][l16] = m;
        sm_l[sp][qg][l16] = l;
    }
    __syncthreads();

#pragma unroll
    for (int e = 0; e < 4; ++e) {
        const int idx = e * 512 + tid;      // 0..2047
        const int row = idx >> 6;           // 0..31
        const int col = idx & 63;
        const int qg2 = row >> 4, r16 = row & 15;
        float M = sm_m[0][qg2][r16];
#pragma unroll
        for (int s2 = 1; s2 < 4; ++s2) M = fmaxf(M, sm_m[s2][qg2][r16]);
        float L = 0.f, accv = 0.f;
#pragma unroll
        for (int s2 = 0; s2 < 4; ++s2) {
            const float w = __expf(sm_m[s2][qg2][r16] - M);
            L += w * sm_l[s2][qg2][r16];
            accv += w * sm_o[s2][qg2][r16][col];
        }
        out[((size_t)b * NT + blockIdx.x * 32 + row) * NH + col] = accv / L;
    }
}

extern "C" void kernel_launch(void* const* d_in, const int* in_sizes, int n_in,
                              void* d_out, int out_size, void* d_ws, size_t ws_size,
                              hipStream_t stream) {
    const float* x    = (const float*)d_in[0];
    const int*   mask = (const int*)d_in[1];
    const float* Wk   = (const float*)d_in[2];
    const float* Wq   = (const float*)d_in[3];
    const float* Wv   = (const float*)d_in[4];
    float* out = (float*)d_out;

    char* ws = (char*)d_ws;
    bf16* Wt = (bf16*)(ws);                                   // 384 KiB
    bf16* qp = (bf16*)(ws + (512 << 10));                     // 2 MiB
    bf16* kp = (bf16*)(ws + (512 << 10) + (2 << 20));         // 2 MiB
    bf16* vt = (bf16*)(ws + (512 << 10) + (4 << 20));         // 2 MiB

    pack_w<<<dim3(768), dim3(256), 0, stream>>>(Wq, Wk, Wv, Wt);
    qkv_gemm<<<dim3(512), dim3(256), 0, stream>>>(x, Wt, qp, kp, vt);
    attn<<<dim3(64, 8), dim3(512), 0, stream>>>(qp, kp, vt, mask, out);
}

// Round 4
// 125.733 us; speedup vs baseline: 1.2281x; 1.0138x over previous
//
#include <hip/hip_runtime.h>
#include <hip/hip_bf16.h>

typedef __bf16 bf16;
typedef __bf16 bf16x4 __attribute__((ext_vector_type(4)));
typedef __bf16 bf16x8 __attribute__((ext_vector_type(8)));
typedef float f32x4 __attribute__((ext_vector_type(4)));

#define NB 8
#define NT 2048
#define NC 1024
#define NH 64

__device__ inline f32x4 zero4() {
    f32x4 z; z[0] = 0.f; z[1] = 0.f; z[2] = 0.f; z[3] = 0.f; return z;
}

// ---------------- pack W: Wq|Wk|Wv (f32 [C][H]) -> Wt bf16 [192][C] (B^T layout) ----
__global__ __launch_bounds__(256) void pack_w(const float* __restrict__ Wq,
                                              const float* __restrict__ Wk,
                                              const float* __restrict__ Wv,
                                              bf16* __restrict__ Wt) {
    const int idx = blockIdx.x * 256 + threadIdx.x;   // n*1024 + c
    const int n = idx >> 10;
    const int c = idx & 1023;
    const float* W = (n < 64) ? Wq : (n < 128) ? Wk : Wv;
    Wt[idx] = (bf16)W[c * NH + (n & 63)];
}

// ---------------- QKV projection ----------------
// 512 blocks x 256 threads = 32 rows x 192 cols. Wave: qg(2) x ch(2, 96 cols).
// 3-deep x register pipeline (HBM latency covered at distance 2), B-fragment
// register double-buffer at distance 1 (L2), single barrier/iter.
// launch_bounds(256,2): 256-VGPR budget so the scheduler keeps loads parallel.
__global__ __launch_bounds__(256, 2) void qkv_gemm(const float* __restrict__ x,
                                                   const bf16* __restrict__ Wt,
                                                   bf16* __restrict__ qp,
                                                   bf16* __restrict__ kp,
                                                   bf16* __restrict__ vt) {
    __shared__ bf16 xs[2][32][72];   // double-buffered, +8 pad
    const int tid = threadIdx.x;
    const int wave = tid >> 6, lane = tid & 63;
    const int l16 = lane & 15, lhi = lane >> 4;
    const int qg = wave & 1;      // 16-row group
    const int ch = wave >> 1;     // 96-col half
    const int row0 = blockIdx.x * 32;

    f32x4 acc[6];
#pragma unroll
    for (int nf = 0; nf < 6; ++nf) acc[nf] = zero4();

    const int sr = tid >> 4;           // 0..15 (rows sr, sr+16)
    const int sc = (tid & 15) * 4;     // f32 col

    float4 xv[3][2];     // 3-deep x pipeline
    bf16x8 bfr[2][12];   // B-fragment double buffer

#define LOAD_X(SLOT, KT)  do { \
    xv[SLOT][0] = *reinterpret_cast<const float4*>(&x[(size_t)(row0 + sr) * NC + (KT) * 64 + sc]); \
    xv[SLOT][1] = *reinterpret_cast<const float4*>(&x[(size_t)(row0 + sr + 16) * NC + (KT) * 64 + sc]); \
} while (0)

#define LOAD_B(SLOT, KT)  do { \
    _Pragma("unroll") for (int _nf = 0; _nf < 6; ++_nf) \
        _Pragma("unroll") for (int _kc = 0; _kc < 2; ++_kc) \
            bfr[SLOT][_nf * 2 + _kc] = *reinterpret_cast<const bf16x8*>( \
                &Wt[(size_t)(ch * 96 + _nf * 16 + l16) * NC + (KT) * 64 + _kc * 32 + lhi * 8]); \
} while (0)

#define WRITE_XS(BUF, SLOT)  do { \
    bf16x4 _w0, _w1; \
    _w0[0] = (bf16)xv[SLOT][0].x; _w0[1] = (bf16)xv[SLOT][0].y; \
    _w0[2] = (bf16)xv[SLOT][0].z; _w0[3] = (bf16)xv[SLOT][0].w; \
    _w1[0] = (bf16)xv[SLOT][1].x; _w1[1] = (bf16)xv[SLOT][1].y; \
    _w1[2] = (bf16)xv[SLOT][1].z; _w1[3] = (bf16)xv[SLOT][1].w; \
    *reinterpret_cast<bf16x4*>(&xs[BUF][sr][sc]) = _w0; \
    *reinterpret_cast<bf16x4*>(&xs[BUF][sr + 16][sc]) = _w1; \
} while (0)

    // prologue: x(0),x(1),x(2) and B(0) in flight; stage x(0)
    LOAD_X(0, 0);
    LOAD_X(1, 1);
    LOAD_X(2, 2);
    LOAD_B(0, 0);
    WRITE_XS(0, 0);
    __syncthreads();

#pragma unroll
    for (int kt = 0; kt < 16; ++kt) {
        const int cur = kt & 1, nxt = cur ^ 1;
        // issue x(kt+3) into the freed slot (distance 2 from its LDS write)
        if (kt < 13) LOAD_X(kt % 3, kt + 3);
        // a-fragments for this k-chunk
        bf16x8 a[2];
#pragma unroll
        for (int kc = 0; kc < 2; ++kc)
            a[kc] = *reinterpret_cast<const bf16x8*>(
                &xs[cur][qg * 16 + l16][kc * 32 + lhi * 8]);
        // stage x(kt+1) (loads issued 2 iterations ago -> no stall)
        if (kt < 15) WRITE_XS(nxt, (kt + 1) % 3);
        // issue B(kt+1)
        if (kt < 15) LOAD_B(nxt, kt + 1);
        __syncthreads();
        __builtin_amdgcn_s_setprio(1);
#pragma unroll
        for (int nf = 0; nf < 6; ++nf)
#pragma unroll
            for (int kc = 0; kc < 2; ++kc)
                acc[nf] = __builtin_amdgcn_mfma_f32_16x16x32_bf16(a[kc], bfr[cur][nf * 2 + kc], acc[nf], 0, 0, 0);
        __builtin_amdgcn_s_setprio(0);
    }
#undef LOAD_X
#undef LOAD_B
#undef WRITE_XS

#pragma unroll
    for (int nf = 0; nf < 6; ++nf) {
        const int col = ch * 96 + nf * 16 + l16;
#pragma unroll
        for (int r = 0; r < 4; ++r) {
            const int row = row0 + qg * 16 + lhi * 4 + r;
            const bf16 val = (bf16)acc[nf][r];
            if (col < 64) {
                qp[(size_t)row * NH + col] = val;
            } else if (col < 128) {
                kp[(size_t)row * NH + (col - 64)] = val;
            } else {
                const int bb = row >> 11, t = row & (NT - 1), h = col - 128;
                vt[(((size_t)bb * NH + h) << 11) + t] = val;
            }
        }
    }
}

// ---------------- fused flash attention, reg-double-buffered K/V prefetch ----
// grid (64, 8): 32 q-rows/block. 512 threads = 8 waves = qg(2) x kvsplit(4).
// Swapped QK^T (P lane-local in q), per-wave P relayout through LDS, no intra-loop
// barriers. K/V tile it+1 prefetched into registers while tile it computes;
// sched_barrier(0) pins the prefetch issue above the compute.
__global__ __launch_bounds__(512, 2) void attn(const bf16* __restrict__ qp,
                                               const bf16* __restrict__ kp,
                                               const bf16* __restrict__ vt,
                                               const int* __restrict__ mask,
                                               float* __restrict__ out) {
    __shared__ __align__(16) char smem[4 * 2 * 16 * 68 * 4];   // 34816 B (union)
    bf16 (*p_lds)[64][20] = reinterpret_cast<bf16 (*)[64][20]>(smem);   // [8][64][20]
    float (*sm_o)[2][16][68] = reinterpret_cast<float (*)[2][16][68]>(smem);
    __shared__ float sm_m[4][2][16], sm_l[4][2][16];

    const int tid = threadIdx.x;
    const int wave = tid >> 6, lane = tid & 63;
    const int l16 = lane & 15, lhi = lane >> 4;
    const int b = blockIdx.y;
    const int qg = wave & 1, sp = wave >> 1;
    const int q0 = blockIdx.x * 32 + qg * 16;
    const int kv_lo = sp * 512;
    bf16* const pw = &p_lds[wave][0][0];

    bf16x8 aq[2];
#pragma unroll
    for (int hc = 0; hc < 2; ++hc)
        aq[hc] = *reinterpret_cast<const bf16x8*>(
            &qp[((size_t)b * NT + q0 + l16) * NH + hc * 32 + lhi * 8]);

    bf16x8 kr[2][8], vr[2][8];   // [phase][...], phase index compile-time via unroll

#define LOAD_TILE(S, IT)  do { \
    const int _kv0 = kv_lo + (IT) * 64; \
    _Pragma("unroll") for (int _kvb = 0; _kvb < 4; ++_kvb) \
        _Pragma("unroll") for (int _hc = 0; _hc < 2; ++_hc) \
            kr[S][_kvb * 2 + _hc] = *reinterpret_cast<const bf16x8*>( \
                &kp[((size_t)b * NT + _kv0 + _kvb * 16 + l16) * NH + _hc * 32 + lhi * 8]); \
    _Pragma("unroll") for (int _kc = 0; _kc < 2; ++_kc) \
        _Pragma("unroll") for (int _hb = 0; _hb < 4; ++_hb) \
            vr[S][_kc * 4 + _hb] = *reinterpret_cast<const bf16x8*>( \
                &vt[((size_t)b * NH + _hb * 16 + l16) * NT + _kv0 + _kc * 32 + lhi * 8]); \
} while (0)

    float m = -1e30f, l = 0.f;
    f32x4 o[4];
#pragma unroll
    for (int hb = 0; hb < 4; ++hb) o[hb] = zero4();

    LOAD_TILE(0, 0);

#pragma unroll
    for (int it = 0; it < 8; ++it) {
        const int cur = it & 1, nxt = cur ^ 1;
        const int kv0 = kv_lo + it * 64;
        // prefetch next tile; pin above compute
        if (it < 7) LOAD_TILE(nxt, it + 1);
        // mask for this tile (L2-hot, overlaps QK MFMAs)
        int4 mvv[4];
#pragma unroll
        for (int kvb = 0; kvb < 4; ++kvb)
            mvv[kvb] = *reinterpret_cast<const int4*>(&mask[b * NT + kv0 + kvb * 16 + lhi * 4]);
        __builtin_amdgcn_sched_barrier(0);

        // S^T = K Q^T
        f32x4 s[4];
        __builtin_amdgcn_s_setprio(1);
#pragma unroll
        for (int kvb = 0; kvb < 4; ++kvb) {
            s[kvb] = zero4();
#pragma unroll
            for (int hc = 0; hc < 2; ++hc)
                s[kvb] = __builtin_amdgcn_mfma_f32_16x16x32_bf16(kr[cur][kvb * 2 + hc], aq[hc], s[kvb], 0, 0, 0);
        }
        __builtin_amdgcn_s_setprio(0);
        // mask + scale: element r <-> kv = kv0 + kvb*16 + lhi*4 + r
#pragma unroll
        for (int kvb = 0; kvb < 4; ++kvb) {
            const int mm[4] = {mvv[kvb].x, mvv[kvb].y, mvv[kvb].z, mvv[kvb].w};
#pragma unroll
            for (int r = 0; r < 4; ++r)
                s[kvb][r] = mm[r] ? s[kvb][r] * 0.125f : -1e30f;
        }
        // online softmax (row q = l16 is lane-local)
        float tm = s[0][0];
#pragma unroll
        for (int kvb = 0; kvb < 4; ++kvb)
#pragma unroll
            for (int r = 0; r < 4; ++r) tm = fmaxf(tm, s[kvb][r]);
        tm = fmaxf(tm, __shfl_xor(tm, 16));
        tm = fmaxf(tm, __shfl_xor(tm, 32));
        const float mn = fmaxf(m, tm);
        const float alpha = __expf(m - mn);
        m = mn;
        float ps = 0.f;
#pragma unroll
        for (int kvb = 0; kvb < 4; ++kvb)
#pragma unroll
            for (int r = 0; r < 4; ++r) {
                const float p = __expf(s[kvb][r] - m);
                s[kvb][r] = p;
                ps += p;
            }
        ps += __shfl_xor(ps, 16);
        ps += __shfl_xor(ps, 32);
        l = l * alpha + ps;
        // pack P -> per-wave LDS (A-frag ordered); wave-local, no barrier
#pragma unroll
        for (int kvb = 0; kvb < 4; ++kvb) {
            bf16x4 w;
            w[0] = (bf16)s[kvb][0]; w[1] = (bf16)s[kvb][1];
            w[2] = (bf16)s[kvb][2]; w[3] = (bf16)s[kvb][3];
            const int row = l16 + 16 * ((kvb * 2 + (lhi >> 1)) & 3);
            *reinterpret_cast<bf16x4*>(pw + row * 20 + (kvb >> 1) * 8 + (lhi & 1) * 4) = w;
        }
        // broadcast alpha to O-row layout, rescale O
        float ar[4];
#pragma unroll
        for (int r = 0; r < 4; ++r) ar[r] = __shfl(alpha, lhi * 4 + r);
#pragma unroll
        for (int hb = 0; hb < 4; ++hb)
#pragma unroll
            for (int r = 0; r < 4; ++r) o[hb][r] *= ar[r];
        // O += P V
        __builtin_amdgcn_s_setprio(1);
#pragma unroll
        for (int kc = 0; kc < 2; ++kc) {
            const bf16* pr = pw + lane * 20 + kc * 8;
            const bf16x4 lo = *reinterpret_cast<const bf16x4*>(pr);
            const bf16x4 hi = *reinterpret_cast<const bf16x4*>(pr + 4);
            const bf16x8 pa = __builtin_shufflevector(lo, hi, 0, 1, 2, 3, 4, 5, 6, 7);
#pragma unroll
            for (int hb = 0; hb < 4; ++hb)
                o[hb] = __builtin_amdgcn_mfma_f32_16x16x32_bf16(pa, vr[cur][kc * 4 + hb], o[hb], 0, 0, 0);
        }
        __builtin_amdgcn_s_setprio(0);
    }
#undef LOAD_TILE

    // ---- combine the 4 KV splits through LDS ----
    __syncthreads();   // all waves done with p_lds (aliased by sm_o)
#pragma unroll
    for (int hb = 0; hb < 4; ++hb)
#pragma unroll
        for (int r = 0; r < 4; ++r)
            sm_o[sp][qg][lhi * 4 + r][hb * 16 + l16] = o[hb][r];
    if (lhi == 0) {
        sm_m[sp][qg][l16] = m;
        sm_l[sp][qg][l16] = l;
    }
    __syncthreads();

#pragma unroll
    for (int e = 0; e < 4; ++e) {
        const int idx = e * 512 + tid;      // 0..2047
        const int row = idx >> 6;           // 0..31
        const int col = idx & 63;
        const int qg2 = row >> 4, r16 = row & 15;
        float M = sm_m[0][qg2][r16];
#pragma unroll
        for (int s2 = 1; s2 < 4; ++s2) M = fmaxf(M, sm_m[s2][qg2][r16]);
        float L = 0.f, accv = 0.f;
#pragma unroll
        for (int s2 = 0; s2 < 4; ++s2) {
            const float w = __expf(sm_m[s2][qg2][r16] - M);
            L += w * sm_l[s2][qg2][r16];
            accv += w * sm_o[s2][qg2][r16][col];
        }
        out[((size_t)b * NT + blockIdx.x * 32 + row) * NH + col] = accv / L;
    }
}

extern "C" void kernel_launch(void* const* d_in, const int* in_sizes, int n_in,
                              void* d_out, int out_size, void* d_ws, size_t ws_size,
                              hipStream_t stream) {
    const float* x    = (const float*)d_in[0];
    const int*   mask = (const int*)d_in[1];
    const float* Wk   = (const float*)d_in[2];
    const float* Wq   = (const float*)d_in[3];
    const float* Wv   = (const float*)d_in[4];
    float* out = (float*)d_out;

    char* ws = (char*)d_ws;
    bf16* Wt = (bf16*)(ws);                                   // 384 KiB
    bf16* qp = (bf16*)(ws + (512 << 10));                     // 2 MiB
    bf16* kp = (bf16*)(ws + (512 << 10) + (2 << 20));         // 2 MiB
    bf16* vt = (bf16*)(ws + (512 << 10) + (4 << 20));         // 2 MiB

    pack_w<<<dim3(768), dim3(256), 0, stream>>>(Wq, Wk, Wv, Wt);
    qkv_gemm<<<dim3(512), dim3(256), 0, stream>>>(x, Wt, qp, kp, vt);
    attn<<<dim3(64, 8), dim3(512), 0, stream>>>(qp, kp, vt, mask, out);
}

// Round 5
// 58.163 us; speedup vs baseline: 2.6547x; 2.1617x over previous
//
#include <hip/hip_runtime.h>
#include <hip/hip_bf16.h>

typedef __bf16 bf16;
typedef __bf16 bf16x4 __attribute__((ext_vector_type(4)));
typedef __bf16 bf16x8 __attribute__((ext_vector_type(8)));
typedef float f32x4 __attribute__((ext_vector_type(4)));

#define NB 8
#define NT 2048
#define NC 1024
#define NH 64

__device__ inline f32x4 zero4() {
    f32x4 z; z[0] = 0.f; z[1] = 0.f; z[2] = 0.f; z[3] = 0.f; return z;
}

// ---------------- pack W into MFMA-fragment order ----------------
// Wt2[(((nf*16+kt)*2+kc)*64+l)*8+e] = W^T[n = nf*16+(l&15)][k = kt*64+kc*32+(l>>4)*8+e]
// (n: 0-63 Wq, 64-127 Wk, 128-191 Wv; W^T[n][k] = W[k*64 + (n&63)])
__global__ __launch_bounds__(256) void pack_w(const float* __restrict__ Wq,
                                              const float* __restrict__ Wk,
                                              const float* __restrict__ Wv,
                                              bf16* __restrict__ Wt2) {
    const int g = blockIdx.x * 256 + threadIdx.x;   // 0..24575
    const int l = g & 63;
    const int kc = (g >> 6) & 1;
    const int kt = (g >> 7) & 15;
    const int nf = g >> 11;                          // 0..11
    const int n = nf * 16 + (l & 15);
    const int k0 = kt * 64 + kc * 32 + (l >> 4) * 8;
    const float* W = (n < 64) ? Wq : (n < 128) ? Wk : Wv;
    const int h = n & 63;
    bf16x8 o;
#pragma unroll
    for (int e = 0; e < 8; ++e) o[e] = (bf16)W[(k0 + e) * NH + h];
    *reinterpret_cast<bf16x8*>(Wt2 + (size_t)g * 8) = o;
}

// ---------------- QKV projection ----------------
// 512 blocks x 256 threads = 32 rows x 192 cols. Wave: qg(2) x ch(2, 96 cols).
// B-fragments from Wt2 (fragment order -> 1-clause coalesced loads).
__global__ __launch_bounds__(256, 2) void qkv_gemm(const float* __restrict__ x,
                                                   const bf16* __restrict__ Wt2,
                                                   bf16* __restrict__ qp,
                                                   bf16* __restrict__ kp2,
                                                   bf16* __restrict__ vt2) {
    __shared__ bf16 xs[2][32][72];   // double-buffered, +8 pad
    const int tid = threadIdx.x;
    const int wave = tid >> 6, lane = tid & 63;
    const int l16 = lane & 15, lhi = lane >> 4;
    const int qg = wave & 1;      // 16-row group
    const int ch = wave >> 1;     // 96-col half
    const int row0 = blockIdx.x * 32;
    const bf16* wb = Wt2 + (size_t)ch * 98304 + lane * 8;   // + nf*16384 + kt*1024 + kc*512

    f32x4 acc[6];
#pragma unroll
    for (int nf = 0; nf < 6; ++nf) acc[nf] = zero4();

    const int sr = tid >> 4;           // 0..15 (rows sr, sr+16)
    const int sc = (tid & 15) * 4;     // f32 col

    float4 xv[3][2];     // 3-deep x pipeline
    bf16x8 bfr[2][12];   // B-fragment double buffer

#define LOAD_X(SLOT, KT)  do { \
    xv[SLOT][0] = *reinterpret_cast<const float4*>(&x[(size_t)(row0 + sr) * NC + (KT) * 64 + sc]); \
    xv[SLOT][1] = *reinterpret_cast<const float4*>(&x[(size_t)(row0 + sr + 16) * NC + (KT) * 64 + sc]); \
} while (0)

#define LOAD_B(SLOT, KT)  do { \
    _Pragma("unroll") for (int _nf = 0; _nf < 6; ++_nf) \
        _Pragma("unroll") for (int _kc = 0; _kc < 2; ++_kc) \
            bfr[SLOT][_nf * 2 + _kc] = *reinterpret_cast<const bf16x8*>( \
                wb + _nf * 16384 + (KT) * 1024 + _kc * 512); \
} while (0)

#define WRITE_XS(BUF, SLOT)  do { \
    bf16x4 _w0, _w1; \
    _w0[0] = (bf16)xv[SLOT][0].x; _w0[1] = (bf16)xv[SLOT][0].y; \
    _w0[2] = (bf16)xv[SLOT][0].z; _w0[3] = (bf16)xv[SLOT][0].w; \
    _w1[0] = (bf16)xv[SLOT][1].x; _w1[1] = (bf16)xv[SLOT][1].y; \
    _w1[2] = (bf16)xv[SLOT][1].z; _w1[3] = (bf16)xv[SLOT][1].w; \
    *reinterpret_cast<bf16x4*>(&xs[BUF][sr][sc]) = _w0; \
    *reinterpret_cast<bf16x4*>(&xs[BUF][sr + 16][sc]) = _w1; \
} while (0)

    LOAD_X(0, 0);
    LOAD_X(1, 1);
    LOAD_X(2, 2);
    LOAD_B(0, 0);
    WRITE_XS(0, 0);
    __syncthreads();

#pragma unroll
    for (int kt = 0; kt < 16; ++kt) {
        const int cur = kt & 1, nxt = cur ^ 1;
        if (kt < 13) LOAD_X(kt % 3, kt + 3);
        bf16x8 a[2];
#pragma unroll
        for (int kc = 0; kc < 2; ++kc)
            a[kc] = *reinterpret_cast<const bf16x8*>(
                &xs[cur][qg * 16 + l16][kc * 32 + lhi * 8]);
        if (kt < 15) WRITE_XS(nxt, (kt + 1) % 3);
        if (kt < 15) LOAD_B(nxt, kt + 1);
        __syncthreads();
        __builtin_amdgcn_s_setprio(1);
#pragma unroll
        for (int nf = 0; nf < 6; ++nf)
#pragma unroll
            for (int kc = 0; kc < 2; ++kc)
                acc[nf] = __builtin_amdgcn_mfma_f32_16x16x32_bf16(a[kc], bfr[cur][nf * 2 + kc], acc[nf], 0, 0, 0);
        __builtin_amdgcn_s_setprio(0);
    }
#undef LOAD_X
#undef LOAD_B
#undef WRITE_XS

    // epilogue: q row-major; k,v scattered into fragment-order kp2/vt2
#pragma unroll
    for (int nf = 0; nf < 6; ++nf) {
        const int col = ch * 96 + nf * 16 + l16;
#pragma unroll
        for (int r = 0; r < 4; ++r) {
            const int row = row0 + qg * 16 + lhi * 4 + r;
            const bf16 val = (bf16)acc[nf][r];
            const int bb = row >> 11, kv = row & (NT - 1);
            const int t = kv >> 6;
            if (col < 64) {
                qp[(size_t)row * NH + col] = val;
            } else if (col < 128) {
                const int h = col - 64;
                const int kvb = (kv >> 4) & 3;
                const int lK = ((h & 31) >> 3) * 16 + (kv & 15);
                kp2[((((size_t)(bb * 32 + t) * 4 + kvb) * 2 + (h >> 5)) * 64 + lK) * 8 + (h & 7)] = val;
            } else {
                const int h = col - 128;
                const int kcV = (kv >> 5) & 1;
                const int lV = ((kv & 31) >> 3) * 16 + (h & 15);
                vt2[((((size_t)(bb * 32 + t) * 2 + kcV) * 4 + (h >> 4)) * 64 + lV) * 8 + (kv & 7)] = val;
            }
        }
    }
}

// ---------------- fused flash attention ----------------
// grid (64, 8): 32 q-rows/block. 512 threads = 8 waves = qg(2) x kvsplit(4).
// K/V in fragment-order global layout -> every load is one coalesced clause.
// Fat iterations: 128 KV rows each (2 sub-tiles), one softmax per iteration.
__global__ __launch_bounds__(512) void attn(const bf16* __restrict__ qp,
                                            const bf16* __restrict__ kp2,
                                            const bf16* __restrict__ vt2,
                                            const int* __restrict__ mask,
                                            float* __restrict__ out) {
    __shared__ __align__(16) char smem[4 * 2 * 16 * 68 * 4];   // 34816 B (union)
    bf16 (*p_lds)[64][20] = reinterpret_cast<bf16 (*)[64][20]>(smem);   // [8][64][20]
    float (*sm_o)[2][16][68] = reinterpret_cast<float (*)[2][16][68]>(smem);
    __shared__ float sm_m[4][2][16], sm_l[4][2][16];

    const int tid = threadIdx.x;
    const int wave = tid >> 6, lane = tid & 63;
    const int l16 = lane & 15, lhi = lane >> 4;
    const int b = blockIdx.y;
    const int qg = wave & 1, sp = wave >> 1;
    const int q0 = blockIdx.x * 32 + qg * 16;
    const int tb = sp * 8;                      // first 64-row KV tile of this split
    bf16* const pw = &p_lds[wave][0][0];

    bf16x8 aq[2];
#pragma unroll
    for (int hc = 0; hc < 2; ++hc)
        aq[hc] = *reinterpret_cast<const bf16x8*>(
            &qp[((size_t)b * NT + q0 + l16) * NH + hc * 32 + lhi * 8]);

    // fragment-order bases (each frag load: base + const_offset + lane*8 elems)
    const bf16* kw = kp2 + (size_t)b * 131072 + (size_t)tb * 4096 + lane * 8;
    const bf16* vw = vt2 + (size_t)b * 131072 + (size_t)tb * 4096 + lane * 8;
    const int*  mw = mask + b * NT + tb * 64 + lhi * 4;

    float m = -1e30f, l = 0.f;
    f32x4 o[4];
#pragma unroll
    for (int hb = 0; hb < 4; ++hb) o[hb] = zero4();

#pragma unroll
    for (int f = 0; f < 4; ++f) {
        const int fo = f * 8192;   // two 64-row tiles per fat iteration
        // ---- issue all K loads (1 clause each) ----
        bf16x8 kf[16];   // [sub][kvb][hc]
#pragma unroll
        for (int i = 0; i < 16; ++i) {
            const int sub = i >> 3, kvb = (i >> 1) & 3, hc = i & 1;
            kf[i] = *reinterpret_cast<const bf16x8*>(kw + fo + sub * 4096 + (kvb * 2 + hc) * 512);
        }
        // mask words for both sub-tiles
        int4 mv[8];
#pragma unroll
        for (int j = 0; j < 8; ++j) {
            const int sub = j >> 2, kvb = j & 3;
            mv[j] = *reinterpret_cast<const int4*>(mw + f * 128 + sub * 64 + kvb * 16);
        }
        // ---- QK^T (swapped: A=K, B=Q) ----
        f32x4 s[8];   // [sub*4+kvb], element r <-> kv = tile*64 + kvb*16 + lhi*4 + r
        __builtin_amdgcn_s_setprio(1);
#pragma unroll
        for (int j = 0; j < 8; ++j) {
            s[j] = zero4();
            s[j] = __builtin_amdgcn_mfma_f32_16x16x32_bf16(kf[j * 2], aq[0], s[j], 0, 0, 0);
            s[j] = __builtin_amdgcn_mfma_f32_16x16x32_bf16(kf[j * 2 + 1], aq[1], s[j], 0, 0, 0);
        }
        __builtin_amdgcn_s_setprio(0);
        // ---- issue all V loads (latency hides under softmax) ----
        bf16x8 vf[16];   // [sub][kc][hb]
#pragma unroll
        for (int i = 0; i < 16; ++i) {
            const int sub = i >> 3, kc = (i >> 2) & 1, hb = i & 3;
            vf[i] = *reinterpret_cast<const bf16x8*>(vw + fo + sub * 4096 + kc * 2048 + hb * 512);
        }
        // ---- mask + scale ----
#pragma unroll
        for (int j = 0; j < 8; ++j) {
            s[j][0] = mv[j].x ? s[j][0] * 0.125f : -1e30f;
            s[j][1] = mv[j].y ? s[j][1] * 0.125f : -1e30f;
            s[j][2] = mv[j].z ? s[j][2] * 0.125f : -1e30f;
            s[j][3] = mv[j].w ? s[j][3] * 0.125f : -1e30f;
        }
        // ---- one online-softmax step for 32 values ----
        float tm = s[0][0];
#pragma unroll
        for (int j = 0; j < 8; ++j)
#pragma unroll
            for (int r = 0; r < 4; ++r) tm = fmaxf(tm, s[j][r]);
        tm = fmaxf(tm, __shfl_xor(tm, 16));
        tm = fmaxf(tm, __shfl_xor(tm, 32));
        const float mn = fmaxf(m, tm);
        const float alpha = __expf(m - mn);
        m = mn;
        float ps = 0.f;
#pragma unroll
        for (int j = 0; j < 8; ++j)
#pragma unroll
            for (int r = 0; r < 4; ++r) {
                const float p = __expf(s[j][r] - m);
                s[j][r] = p;
                ps += p;
            }
        ps += __shfl_xor(ps, 16);
        ps += __shfl_xor(ps, 32);
        l = l * alpha + ps;
        // ---- rescale O once per fat iteration ----
        float ar[4];
#pragma unroll
        for (int r = 0; r < 4; ++r) ar[r] = __shfl(alpha, lhi * 4 + r);
#pragma unroll
        for (int hb = 0; hb < 4; ++hb)
#pragma unroll
            for (int r = 0; r < 4; ++r) o[hb][r] *= ar[r];
        // ---- per sub-tile: pack P -> wave-private LDS, then O += P V ----
#pragma unroll
        for (int sub = 0; sub < 2; ++sub) {
#pragma unroll
            for (int kvb = 0; kvb < 4; ++kvb) {
                bf16x4 w;
                w[0] = (bf16)s[sub * 4 + kvb][0]; w[1] = (bf16)s[sub * 4 + kvb][1];
                w[2] = (bf16)s[sub * 4 + kvb][2]; w[3] = (bf16)s[sub * 4 + kvb][3];
                const int row = l16 + 16 * ((kvb * 2 + (lhi >> 1)) & 3);
                *reinterpret_cast<bf16x4*>(pw + row * 20 + (kvb >> 1) * 8 + (lhi & 1) * 4) = w;
            }
            __builtin_amdgcn_s_setprio(1);
#pragma unroll
            for (int kc = 0; kc < 2; ++kc) {
                const bf16* pr = pw + lane * 20 + kc * 8;
                const bf16x4 lo = *reinterpret_cast<const bf16x4*>(pr);
                const bf16x4 hi = *reinterpret_cast<const bf16x4*>(pr + 4);
                const bf16x8 pa = __builtin_shufflevector(lo, hi, 0, 1, 2, 3, 4, 5, 6, 7);
#pragma unroll
                for (int hb = 0; hb < 4; ++hb)
                    o[hb] = __builtin_amdgcn_mfma_f32_16x16x32_bf16(pa, vf[sub * 8 + kc * 4 + hb], o[hb], 0, 0, 0);
            }
            __builtin_amdgcn_s_setprio(0);
        }
    }

    // ---- combine the 4 KV splits through LDS ----
    __syncthreads();   // all waves done with p_lds (aliased by sm_o)
#pragma unroll
    for (int hb = 0; hb < 4; ++hb)
#pragma unroll
        for (int r = 0; r < 4; ++r)
            sm_o[sp][qg][lhi * 4 + r][hb * 16 + l16] = o[hb][r];
    if (lhi == 0) {
        sm_m[sp][qg][l16] = m;
        sm_l[sp][qg][l16] = l;
    }
    __syncthreads();

#pragma unroll
    for (int e = 0; e < 4; ++e) {
        const int idx = e * 512 + tid;      // 0..2047
        const int row = idx >> 6;           // 0..31
        const int col = idx & 63;
        const int qg2 = row >> 4, r16 = row & 15;
        float M = sm_m[0][qg2][r16];
#pragma unroll
        for (int s2 = 1; s2 < 4; ++s2) M = fmaxf(M, sm_m[s2][qg2][r16]);
        float L = 0.f, accv = 0.f;
#pragma unroll
        for (int s2 = 0; s2 < 4; ++s2) {
            const float w = __expf(sm_m[s2][qg2][r16] - M);
            L += w * sm_l[s2][qg2][r16];
            accv += w * sm_o[s2][qg2][r16][col];
        }
        out[((size_t)b * NT + blockIdx.x * 32 + row) * NH + col] = accv / L;
    }
}

extern "C" void kernel_launch(void* const* d_in, const int* in_sizes, int n_in,
                              void* d_out, int out_size, void* d_ws, size_t ws_size,
                              hipStream_t stream) {
    const float* x    = (const float*)d_in[0];
    const int*   mask = (const int*)d_in[1];
    const float* Wk   = (const float*)d_in[2];
    const float* Wq   = (const float*)d_in[3];
    const float* Wv   = (const float*)d_in[4];
    float* out = (float*)d_out;

    char* ws = (char*)d_ws;
    bf16* Wt2 = (bf16*)(ws);                                  // 384 KiB
    bf16* qp  = (bf16*)(ws + (512 << 10));                    // 2 MiB
    bf16* kp2 = (bf16*)(ws + (512 << 10) + (2 << 20));        // 2 MiB
    bf16* vt2 = (bf16*)(ws + (512 << 10) + (4 << 20));        // 2 MiB

    pack_w<<<dim3(96), dim3(256), 0, stream>>>(Wq, Wk, Wv, Wt2);
    qkv_gemm<<<dim3(512), dim3(256), 0, stream>>>(x, Wt2, qp, kp2, vt2);
    attn<<<dim3(64, 8), dim3(512), 0, stream>>>(qp, kp2, vt2, mask, out);
}

// Round 6
// 48.104 us; speedup vs baseline: 3.2098x; 1.2091x over previous
//
#include <hip/hip_runtime.h>
#include <hip/hip_bf16.h>

typedef __bf16 bf16;
typedef __bf16 bf16x4 __attribute__((ext_vector_type(4)));
typedef __bf16 bf16x8 __attribute__((ext_vector_type(8)));
typedef float f32x4 __attribute__((ext_vector_type(4)));

#define NB 8
#define NT 2048
#define NC 1024
#define NH 64

__device__ inline f32x4 zero4() {
    f32x4 z; z[0] = 0.f; z[1] = 0.f; z[2] = 0.f; z[3] = 0.f; return z;
}

// ---------------- pack W into MFMA-fragment order ----------------
// Wt2[(((nf*16+kt)*2+kc)*64+l)*8+e] = W^T[n = nf*16+(l&15)][k = kt*64+kc*32+(l>>4)*8+e]
__global__ __launch_bounds__(256) void pack_w(const float* __restrict__ Wq,
                                              const float* __restrict__ Wk,
                                              const float* __restrict__ Wv,
                                              bf16* __restrict__ Wt2) {
    const int g = blockIdx.x * 256 + threadIdx.x;   // 0..24575
    const int l = g & 63;
    const int kc = (g >> 6) & 1;
    const int kt = (g >> 7) & 15;
    const int nf = g >> 11;                          // 0..11
    const int n = nf * 16 + (l & 15);
    const int k0 = kt * 64 + kc * 32 + (l >> 4) * 8;
    const float* W = (n < 64) ? Wq : (n < 128) ? Wk : Wv;
    const int h = n & 63;
    bf16x8 o;
#pragma unroll
    for (int e = 0; e < 8; ++e) o[e] = (bf16)W[(k0 + e) * NH + h];
    *reinterpret_cast<bf16x8*>(Wt2 + (size_t)g * 8) = o;
}

// ---------------- QKV projection ----------------
// 256 blocks x 256 threads = 64 rows x 192 cols. Wave: qh(2, 32-row half) x ch(2, 96 cols),
// 2-row-rep per wave -> each B fragment feeds 2 MFMAs (B L2 traffic halved vs R5).
__global__ __launch_bounds__(256, 2) void qkv_gemm(const float* __restrict__ x,
                                                   const bf16* __restrict__ Wt2,
                                                   bf16* __restrict__ qp,
                                                   bf16* __restrict__ kp2,
                                                   bf16* __restrict__ vt2) {
    __shared__ bf16 xs[2][64][72];   // double-buffered, +8 pad (18432 B)
    const int tid = threadIdx.x;
    const int wave = tid >> 6, lane = tid & 63;
    const int l16 = lane & 15, lhi = lane >> 4;
    const int qh = wave & 1;      // 32-row half
    const int ch = wave >> 1;     // 96-col half
    const int row0 = blockIdx.x * 64;
    const bf16* wb = Wt2 + (size_t)ch * 98304 + lane * 8;   // + nf*16384 + kt*1024 + kc*512

    f32x4 acc[2][6];   // [mr][nf]
#pragma unroll
    for (int mr = 0; mr < 2; ++mr)
#pragma unroll
        for (int nf = 0; nf < 6; ++nf) acc[mr][nf] = zero4();

    const int sr = tid >> 4;           // 0..15 (rows sr + i*16)
    const int sc = (tid & 15) * 4;     // f32 col

    float4 xv[3][4];     // 3-deep x pipeline, 4 rows/thread
    bf16x8 bfr[2][12];   // B-fragment double buffer

#define LOAD_X(SLOT, KT)  do { \
    _Pragma("unroll") for (int _i = 0; _i < 4; ++_i) \
        xv[SLOT][_i] = *reinterpret_cast<const float4*>( \
            &x[(size_t)(row0 + sr + _i * 16) * NC + (KT) * 64 + sc]); \
} while (0)

#define LOAD_B(SLOT, KT)  do { \
    _Pragma("unroll") for (int _nf = 0; _nf < 6; ++_nf) \
        _Pragma("unroll") for (int _kc = 0; _kc < 2; ++_kc) \
            bfr[SLOT][_nf * 2 + _kc] = *reinterpret_cast<const bf16x8*>( \
                wb + _nf * 16384 + (KT) * 1024 + _kc * 512); \
} while (0)

#define WRITE_XS(BUF, SLOT)  do { \
    _Pragma("unroll") for (int _i = 0; _i < 4; ++_i) { \
        bf16x4 _w; \
        _w[0] = (bf16)xv[SLOT][_i].x; _w[1] = (bf16)xv[SLOT][_i].y; \
        _w[2] = (bf16)xv[SLOT][_i].z; _w[3] = (bf16)xv[SLOT][_i].w; \
        *reinterpret_cast<bf16x4*>(&xs[BUF][sr + _i * 16][sc]) = _w; \
    } \
} while (0)

    LOAD_X(0, 0);
    LOAD_X(1, 1);
    LOAD_X(2, 2);
    LOAD_B(0, 0);
    WRITE_XS(0, 0);
    __syncthreads();

#pragma unroll
    for (int kt = 0; kt < 16; ++kt) {
        const int cur = kt & 1, nxt = cur ^ 1;
        if (kt < 13) LOAD_X(kt % 3, kt + 3);
        bf16x8 a[2][2];   // [mr][kc]
#pragma unroll
        for (int mr = 0; mr < 2; ++mr)
#pragma unroll
            for (int kc = 0; kc < 2; ++kc)
                a[mr][kc] = *reinterpret_cast<const bf16x8*>(
                    &xs[cur][qh * 32 + mr * 16 + l16][kc * 32 + lhi * 8]);
        if (kt < 15) WRITE_XS(nxt, (kt + 1) % 3);
        if (kt < 15) LOAD_B(nxt, kt + 1);
        __syncthreads();
        __builtin_amdgcn_s_setprio(1);
#pragma unroll
        for (int nf = 0; nf < 6; ++nf)
#pragma unroll
            for (int kc = 0; kc < 2; ++kc)
#pragma unroll
                for (int mr = 0; mr < 2; ++mr)
                    acc[mr][nf] = __builtin_amdgcn_mfma_f32_16x16x32_bf16(
                        a[mr][kc], bfr[cur][nf * 2 + kc], acc[mr][nf], 0, 0, 0);
        __builtin_amdgcn_s_setprio(0);
    }
#undef LOAD_X
#undef LOAD_B
#undef WRITE_XS

    // epilogue: q row-major; k,v scattered into fragment-order kp2/vt2
#pragma unroll
    for (int mr = 0; mr < 2; ++mr)
#pragma unroll
    for (int nf = 0; nf < 6; ++nf) {
        const int col = ch * 96 + nf * 16 + l16;
#pragma unroll
        for (int r = 0; r < 4; ++r) {
            const int row = row0 + qh * 32 + mr * 16 + lhi * 4 + r;
            const bf16 val = (bf16)acc[mr][nf][r];
            const int bb = row >> 11, kv = row & (NT - 1);
            const int t = kv >> 6;
            if (col < 64) {
                qp[(size_t)row * NH + col] = val;
            } else if (col < 128) {
                const int h = col - 64;
                const int kvb = (kv >> 4) & 3;
                const int lK = ((h & 31) >> 3) * 16 + (kv & 15);
                kp2[((((size_t)(bb * 32 + t) * 4 + kvb) * 2 + (h >> 5)) * 64 + lK) * 8 + (h & 7)] = val;
            } else {
                const int h = col - 128;
                const int kcV = (kv >> 5) & 1;
                const int lV = ((kv & 31) >> 3) * 16 + (h & 15);
                vt2[((((size_t)(bb * 32 + t) * 2 + kcV) * 4 + (h >> 4)) * 64 + lV) * 8 + (kv & 7)] = val;
            }
        }
    }
}

// ---------------- fused flash attention ----------------
// grid (64, 8): 32 q-rows/block. 256 threads = 4 waves = kvsplit(4).
// Each wave computes BOTH 16-row q-tiles over its 512-KV slice -> every K/V
// fragment load feeds 2x the MFMAs (K/V L2 traffic halved vs R5).
__global__ __launch_bounds__(256, 2) void attn(const bf16* __restrict__ qp,
                                               const bf16* __restrict__ kp2,
                                               const bf16* __restrict__ vt2,
                                               const int* __restrict__ mask,
                                               float* __restrict__ out) {
    __shared__ __align__(16) char smem[4 * 2 * 16 * 68 * 4];   // 34816 B (union)
    bf16 (*p_lds)[64][20] = reinterpret_cast<bf16 (*)[64][20]>(smem);   // [4][64][20]
    float (*sm_o)[2][16][68] = reinterpret_cast<float (*)[2][16][68]>(smem);
    __shared__ float sm_m[4][2][16], sm_l[4][2][16];

    const int tid = threadIdx.x;
    const int sp = tid >> 6, lane = tid & 63;
    const int l16 = lane & 15, lhi = lane >> 4;
    const int b = blockIdx.y;
    const int tb = sp * 8;                      // first 64-row KV tile of this split
    bf16* const pw = &p_lds[sp][0][0];

    // Q fragments for both q-tiles
    bf16x8 aq[2][2];
#pragma unroll
    for (int t = 0; t < 2; ++t)
#pragma unroll
        for (int hc = 0; hc < 2; ++hc)
            aq[t][hc] = *reinterpret_cast<const bf16x8*>(
                &qp[((size_t)b * NT + blockIdx.x * 32 + t * 16 + l16) * NH + hc * 32 + lhi * 8]);

    const bf16* kw = kp2 + (size_t)b * 131072 + (size_t)tb * 4096 + lane * 8;
    const bf16* vw = vt2 + (size_t)b * 131072 + (size_t)tb * 4096 + lane * 8;
    const int*  mw = mask + b * NT + tb * 64 + lhi * 4;

    float m[2] = {-1e30f, -1e30f}, l[2] = {0.f, 0.f};
    f32x4 o[2][4];
#pragma unroll
    for (int t = 0; t < 2; ++t)
#pragma unroll
        for (int hb = 0; hb < 4; ++hb) o[t][hb] = zero4();

#pragma unroll
    for (int it = 0; it < 8; ++it) {
        const int fo = it * 4096;   // one 64-row KV tile
        // ---- K loads (8 one-clause frags) + mask ----
        bf16x8 kf[8];   // [kvb][hc]
#pragma unroll
        for (int i = 0; i < 8; ++i)
            kf[i] = *reinterpret_cast<const bf16x8*>(kw + fo + i * 512);
        int4 mv[4];
#pragma unroll
        for (int kvb = 0; kvb < 4; ++kvb)
            mv[kvb] = *reinterpret_cast<const int4*>(mw + it * 64 + kvb * 16);
        // ---- QK^T for both q-tiles (swapped: A=K, B=Q) ----
        f32x4 s[2][4];
        __builtin_amdgcn_s_setprio(1);
#pragma unroll
        for (int t = 0; t < 2; ++t)
#pragma unroll
            for (int kvb = 0; kvb < 4; ++kvb) {
                s[t][kvb] = zero4();
                s[t][kvb] = __builtin_amdgcn_mfma_f32_16x16x32_bf16(kf[kvb * 2], aq[t][0], s[t][kvb], 0, 0, 0);
                s[t][kvb] = __builtin_amdgcn_mfma_f32_16x16x32_bf16(kf[kvb * 2 + 1], aq[t][1], s[t][kvb], 0, 0, 0);
            }
        __builtin_amdgcn_s_setprio(0);
        // ---- V loads (latency hides under softmax) ----
        bf16x8 vf[8];   // [kc][hb]
#pragma unroll
        for (int i = 0; i < 8; ++i)
            vf[i] = *reinterpret_cast<const bf16x8*>(vw + fo + i * 512);
        // ---- mask + scale ----
#pragma unroll
        for (int t = 0; t < 2; ++t)
#pragma unroll
            for (int kvb = 0; kvb < 4; ++kvb) {
                s[t][kvb][0] = mv[kvb].x ? s[t][kvb][0] * 0.125f : -1e30f;
                s[t][kvb][1] = mv[kvb].y ? s[t][kvb][1] * 0.125f : -1e30f;
                s[t][kvb][2] = mv[kvb].z ? s[t][kvb][2] * 0.125f : -1e30f;
                s[t][kvb][3] = mv[kvb].w ? s[t][kvb][3] * 0.125f : -1e30f;
            }
        // ---- online softmax + P pack + PV, per q-tile ----
#pragma unroll
        for (int t = 0; t < 2; ++t) {
            float tm = s[t][0][0];
#pragma unroll
            for (int kvb = 0; kvb < 4; ++kvb)
#pragma unroll
                for (int r = 0; r < 4; ++r) tm = fmaxf(tm, s[t][kvb][r]);
            tm = fmaxf(tm, __shfl_xor(tm, 16));
            tm = fmaxf(tm, __shfl_xor(tm, 32));
            const float mn = fmaxf(m[t], tm);
            const float alpha = __expf(m[t] - mn);
            m[t] = mn;
            float ps = 0.f;
#pragma unroll
            for (int kvb = 0; kvb < 4; ++kvb)
#pragma unroll
                for (int r = 0; r < 4; ++r) {
                    const float p = __expf(s[t][kvb][r] - m[t]);
                    s[t][kvb][r] = p;
                    ps += p;
                }
            ps += __shfl_xor(ps, 16);
            ps += __shfl_xor(ps, 32);
            l[t] = l[t] * alpha + ps;
            // pack P -> wave-private LDS (A-frag ordered); in-wave DS order is safe
#pragma unroll
            for (int kvb = 0; kvb < 4; ++kvb) {
                bf16x4 w;
                w[0] = (bf16)s[t][kvb][0]; w[1] = (bf16)s[t][kvb][1];
                w[2] = (bf16)s[t][kvb][2]; w[3] = (bf16)s[t][kvb][3];
                const int row = l16 + 16 * ((kvb * 2 + (lhi >> 1)) & 3);
                *reinterpret_cast<bf16x4*>(pw + row * 20 + (kvb >> 1) * 8 + (lhi & 1) * 4) = w;
            }
            // rescale O
            float ar[4];
#pragma unroll
            for (int r = 0; r < 4; ++r) ar[r] = __shfl(alpha, lhi * 4 + r);
#pragma unroll
            for (int hb = 0; hb < 4; ++hb)
#pragma unroll
                for (int r = 0; r < 4; ++r) o[t][hb][r] *= ar[r];
            // O += P V
            __builtin_amdgcn_s_setprio(1);
#pragma unroll
            for (int kc = 0; kc < 2; ++kc) {
                const bf16* pr = pw + lane * 20 + kc * 8;
                const bf16x4 lo = *reinterpret_cast<const bf16x4*>(pr);
                const bf16x4 hi = *reinterpret_cast<const bf16x4*>(pr + 4);
                const bf16x8 pa = __builtin_shufflevector(lo, hi, 0, 1, 2, 3, 4, 5, 6, 7);
#pragma unroll
                for (int hb = 0; hb < 4; ++hb)
                    o[t][hb] = __builtin_amdgcn_mfma_f32_16x16x32_bf16(pa, vf[kc * 4 + hb], o[t][hb], 0, 0, 0);
            }
            __builtin_amdgcn_s_setprio(0);
        }
    }

    // ---- combine the 4 KV splits through LDS ----
    __syncthreads();   // all waves done with p_lds (aliased by sm_o)
#pragma unroll
    for (int t = 0; t < 2; ++t) {
#pragma unroll
        for (int hb = 0; hb < 4; ++hb)
#pragma unroll
            for (int r = 0; r < 4; ++r)
                sm_o[sp][t][lhi * 4 + r][hb * 16 + l16] = o[t][hb][r];
        if (lhi == 0) {
            sm_m[sp][t][l16] = m[t];
            sm_l[sp][t][l16] = l[t];
        }
    }
    __syncthreads();

#pragma unroll
    for (int e = 0; e < 8; ++e) {
        const int idx = e * 256 + tid;      // 0..2047
        const int row = idx >> 6;           // 0..31
        const int col = idx & 63;
        const int t2 = row >> 4, r16 = row & 15;
        float M = sm_m[0][t2][r16];
#pragma unroll
        for (int s2 = 1; s2 < 4; ++s2) M = fmaxf(M, sm_m[s2][t2][r16]);
        float L = 0.f, accv = 0.f;
#pragma unroll
        for (int s2 = 0; s2 < 4; ++s2) {
            const float w = __expf(sm_m[s2][t2][r16] - M);
            L += w * sm_l[s2][t2][r16];
            accv += w * sm_o[s2][t2][r16][col];
        }
        out[((size_t)b * NT + blockIdx.x * 32 + row) * NH + col] = accv / L;
    }
}

extern "C" void kernel_launch(void* const* d_in, const int* in_sizes, int n_in,
                              void* d_out, int out_size, void* d_ws, size_t ws_size,
                              hipStream_t stream) {
    const float* x    = (const float*)d_in[0];
    const int*   mask = (const int*)d_in[1];
    const float* Wk   = (const float*)d_in[2];
    const float* Wq   = (const float*)d_in[3];
    const float* Wv   = (const float*)d_in[4];
    float* out = (float*)d_out;

    char* ws = (char*)d_ws;
    bf16* Wt2 = (bf16*)(ws);                                  // 384 KiB
    bf16* qp  = (bf16*)(ws + (512 << 10));                    // 2 MiB
    bf16* kp2 = (bf16*)(ws + (512 << 10) + (2 << 20));        // 2 MiB
    bf16* vt2 = (bf16*)(ws + (512 << 10) + (4 << 20));        // 2 MiB

    pack_w<<<dim3(96), dim3(256), 0, stream>>>(Wq, Wk, Wv, Wt2);
    qkv_gemm<<<dim3(256), dim3(256), 0, stream>>>(x, Wt2, qp, kp2, vt2);
    attn<<<dim3(64, 8), dim3(256), 0, stream>>>(qp, kp2, vt2, mask, out);
}